// Round 1
// baseline (2833.671 us; speedup 1.0000x reference)
//
#include <hip/hip_runtime.h>
#include <math.h>

// Round 3: swapped-operand 32x32x16 MFMA, nt-parallel waves.
// - 32 edges/block, 4 waves; waves partition the OUTPUT dim, so every weight
//   fragment is fetched from L2 exactly once per block (was 4x).
// - Swapped GEMM1 (A=W1eff, B=feat^T): H lives in registers, edge = lane&31.
//   LN stats = per-lane reg sum + shfl_xor(32) + tiny cross-wave LDS reduce.
// - GEMM2 split-K: normalized H regs become B-frags via v_cvt_pk_bf16_f32 +
//   v_permlane32_swap_b32 (no LDS transpose round-trip); partials summed via
//   ds_add into a zbuf overlaid on the dead feat tile (stride 129).

typedef short short8 __attribute__((ext_vector_type(8)));
typedef float f32x16 __attribute__((ext_vector_type(16)));

#define SFA 392   // k_inv feat row stride (ushorts); 784B = 196 dwords ≡ 4 mod 32
#define SFB 328   // k_mrg feat row stride (ushorts); 656B = 164 dwords ≡ 4 mod 32
#define ZST 129   // zbuf row stride (floats); ≡1 mod 32 -> conflict-free ds_add

__device__ __forceinline__ unsigned short f2bf(float x) {
  union { float f; unsigned u; } v; v.f = x;
  unsigned r = (v.u + 0x7FFFu + ((v.u >> 16) & 1u)) >> 16;
  return (unsigned short)r;
}
__device__ __forceinline__ float silu_f(float x) { return x / (1.0f + __expf(-x)); }
__device__ __forceinline__ unsigned cvtpk(float lo, float hi) {
  unsigned d;
  asm("v_cvt_pk_bf16_f32 %0, %1, %2" : "=v"(d) : "v"(lo), "v"(hi));
  return d;
}

__global__ void k_init(float* __restrict__ node_out, int n, int* __restrict__ last_idx) {
  int i = blockIdx.x * blockDim.x + threadIdx.x;
  if (i == 0) *last_idx = -1;
  for (; i < n; i += gridDim.x * blockDim.x) node_out[i] = 0.0f;
}

__global__ void k_mask(const int* __restrict__ src, const int* __restrict__ dst,
                       int E, unsigned char* __restrict__ rawmask, int* __restrict__ last_idx) {
  int i = blockIdx.x * blockDim.x + threadIdx.x;
  if (i >= E) return;
  int s0 = src[i], d0 = dst[i];
  int s1 = (i + 1 < E) ? src[i + 1] : 0;   // _shift pads 0
  int d1 = (i + 1 < E) ? dst[i + 1] : 0;
  int m = (s0 == s1) && (s0 != d0) && (s1 != d1);
  rawmask[i] = (unsigned char)m;
  if (m) atomicMax(last_idx, i);
}

// Wfa = iw1[:,320:]@aw2 ; cfa = iw1[:,320:]@ab2 ; angle closed-form LN folds.
__global__ void k_setup(const float* __restrict__ iw1, const float* __restrict__ aw2,
                        const float* __restrict__ ab2,
                        const float* __restrict__ aw1, const float* __restrict__ ab1,
                        const float* __restrict__ ag,
                        float* __restrict__ Wfa, float* __restrict__ cfa,
                        float* __restrict__ wg, float* __restrict__ bg,
                        float* __restrict__ angp) {
  int n = blockIdx.x * blockDim.x + threadIdx.x;
  if (n < 384 * 64) {
    int r = n >> 6, j = n & 63;
    float acc = 0.0f;
    for (int k = 0; k < 64; ++k) acc += iw1[r * 384 + 320 + k] * aw2[k * 64 + j];
    Wfa[n] = acc;
  } else if (n < 384 * 64 + 384) {
    int r = n - 384 * 64;
    float acc = 0.0f;
    for (int k = 0; k < 64; ++k) acc += iw1[r * 384 + 320 + k] * ab2[k];
    cfa[r] = acc;
  } else if (n < 384 * 64 + 384 + 64) {
    int j = n - (384 * 64 + 384);
    float wm = 0.f, bm = 0.f;
    for (int k = 0; k < 64; ++k) { wm += aw1[k]; bm += ab1[k]; }
    wm *= (1.f / 64.f); bm *= (1.f / 64.f);
    wg[j] = (aw1[j] - wm) * ag[j];
    bg[j] = (ab1[j] - bm) * ag[j];
    if (j == 0) {
      float vw = 0.f, cwb = 0.f, vb = 0.f;
      for (int k = 0; k < 64; ++k) {
        float dw = aw1[k] - wm, db = ab1[k] - bm;
        vw += dw * dw; cwb += dw * db; vb += db * db;
      }
      angp[0] = vw * (1.f / 64.f);
      angp[1] = cwb * (1.f / 64.f);
      angp[2] = vb * (1.f / 64.f);
    }
  }
}

// Swizzle weights into 32x32x16 A-fragment order:
// frag (nt,kt), lane l: value = W[n = nt*32 + (l&31)][k = kt*16 + ((l>>5)&1)*8 + j].
__global__ void k_swz(const float* __restrict__ iw1, const float* __restrict__ iw2,
                      const float* __restrict__ mw1, const float* __restrict__ mw2,
                      const float* __restrict__ Wfa,
                      unsigned short* __restrict__ B1, unsigned short* __restrict__ B2,
                      unsigned short* __restrict__ B3, unsigned short* __restrict__ B4) {
  const int NC1 = 12 * 24 * 64, NC2 = 4 * 24 * 64, NC3 = 4 * 20 * 64, NC4 = 4 * 8 * 64;
  int cid = blockIdx.x * blockDim.x + threadIdx.x;
  int region, rel, KT;
  unsigned short* out;
  if (cid < NC1)                        { region = 1; rel = cid;                   KT = 24; out = B1; }
  else if (cid < NC1 + NC2)             { region = 2; rel = cid - NC1;             KT = 24; out = B2; }
  else if (cid < NC1 + NC2 + NC3)       { region = 3; rel = cid - NC1 - NC2;       KT = 20; out = B3; }
  else if (cid < NC1 + NC2 + NC3 + NC4) { region = 4; rel = cid - NC1 - NC2 - NC3; KT = 8;  out = B4; }
  else return;
  int l = rel & 63;
  int ktn = rel >> 6;
  int kt = ktn % KT, nt = ktn / KT;
  int n = nt * 32 + (l & 31);
  int k0 = kt * 16 + ((l >> 5) & 1) * 8;
  short8 pk;
  #pragma unroll
  for (int j = 0; j < 8; ++j) {
    int k = k0 + j;
    float v;
    if (region == 1)      v = (k < 320) ? iw1[n * 384 + k] : Wfa[n * 64 + (k - 320)];
    else if (region == 2) v = iw2[n * 384 + k];
    else if (region == 3) v = mw1[n * 320 + k];
    else                  v = mw2[n * 128 + k];
    pk[j] = (short)f2bf(v);
  }
  *(short8*)(out + ((size_t)rel << 3)) = pk;
}

__global__ __launch_bounds__(256, 3)
void k_inv(const float* __restrict__ atom, const float* __restrict__ el,
           const float* __restrict__ ev,
           const int* __restrict__ src, const int* __restrict__ dst,
           const unsigned char* __restrict__ rawmask, const int* __restrict__ last_idx,
           const float* __restrict__ ib1, const float* __restrict__ ig,
           const float* __restrict__ ibn, const float* __restrict__ ib2,
           const float* __restrict__ cfa, const float* __restrict__ wg,
           const float* __restrict__ bg, const float* __restrict__ abn,
           const float* __restrict__ angp,
           const unsigned short* __restrict__ Bsw1, const unsigned short* __restrict__ Bsw2,
           float* __restrict__ node_out, int E) {
  __shared__ __attribute__((aligned(16))) unsigned short sf[32 * SFA];  // 25088 B; zbuf overlay
  __shared__ __attribute__((aligned(16))) float stab[1664];  // ib1|cfa|ig|ibn|ib2
  __shared__ float ssum[128], ssq[128], smean[32], srstd[32];
  __shared__ float scos[32], srr[32], smaskf[32];
  __shared__ int ssrc[32], sdst[32], sdsts[32];

  const int t = threadIdx.x;
  const int lane = t & 63;
  const int w = t >> 6;
  const int e31 = lane & 31;
  const int hi = lane >> 5;
  const int geb = blockIdx.x * 32;
  float* zbuf = (float*)sf;

  // ---- stage bias/LN tables ----
  for (int i = t; i < 1664; i += 256) {
    float v;
    if (i < 384) v = ib1[i];
    else if (i < 768) v = cfa[i - 384];
    else if (i < 1152) v = ig[i - 768];
    else if (i < 1536) v = ibn[i - 1152];
    else v = ib2[i - 1536];
    stab[i] = v;
  }

  // ---- pre-pass: per-edge mask, indices, cos, closed-form angle-LN rstd ----
  if (t < 32) {
    int e = t, ge = geb + e;
    int last = *last_idx;
    int m0 = 0, m1 = 0, s0 = 0, d0v = 0, d1v = 0;
    if (ge < E) { s0 = src[ge]; d0v = dst[ge]; m0 = rawmask[ge] && (ge != last); }
    if (ge + 1 < E) { d1v = dst[ge + 1]; m1 = rawmask[ge + 1] && (ge + 1 != last); }
    ssrc[e] = s0; sdst[e] = d0v; sdsts[e] = d1v;
    smaskf[e] = m0 ? 1.0f : 0.0f;
    float cosv = 0.f;
    if (m0 && m1) {
      float ax = ev[3 * ge], ay = ev[3 * ge + 1], az = ev[3 * ge + 2];
      float bx = ev[3 * ge + 3], by = ev[3 * ge + 4], bz = ev[3 * ge + 5];
      cosv = (ax * bx + ay * by + az * bz) *
             rsqrtf((ax * ax + ay * ay + az * az) * (bx * bx + by * by + bz * bz));
    }
    scos[e] = cosv;
    srr[e] = rsqrtf(cosv * cosv * angp[0] + 2.f * cosv * angp[1] + angp[2] + 1e-6f);
  }
  __syncthreads();

  // ---- stage feat [32][384] bf16 into LDS (mask-zeroed; angle cols closed-form) ----
  #pragma unroll
  for (int ii = 0; ii < 6; ++ii) {
    int cid = t + 256 * ii;          // 1536 chunks of 8
    int e = cid / 48, c0 = (cid % 48) * 8;
    int ge = geb + e;
    float mk = smaskf[e];
    float v[8];
    if (c0 < 320) {
      const float* sp;
      if (c0 < 64)        sp = atom + (size_t)ssrc[e] * 64 + c0;
      else if (c0 < 128)  sp = atom + (size_t)sdst[e] * 64 + (c0 - 64);
      else if (c0 < 192)  sp = el + (size_t)ge * 64 + (c0 - 128);
      else if (c0 < 256)  sp = atom + (size_t)sdsts[e] * 64 + (c0 - 192);
      else                sp = el + (size_t)(ge + 1) * 64 + (c0 - 256);
      bool ld = (ge < E) && (mk > 0.f) && !(c0 >= 256 && ge + 1 >= E);
      if (ld) {
        float4 p0 = *(const float4*)sp;
        float4 p1 = *(const float4*)(sp + 4);
        v[0] = p0.x; v[1] = p0.y; v[2] = p0.z; v[3] = p0.w;
        v[4] = p1.x; v[5] = p1.y; v[6] = p1.z; v[7] = p1.w;
      } else {
        #pragma unroll
        for (int j = 0; j < 8; ++j) v[j] = 0.f;
      }
    } else {
      int j0 = c0 - 320;
      float cosv = scos[e], rr = srr[e];
      float4 w0 = *(const float4*)(wg + j0),  w1 = *(const float4*)(wg + j0 + 4);
      float4 g0 = *(const float4*)(bg + j0),  g1 = *(const float4*)(bg + j0 + 4);
      float4 n0 = *(const float4*)(abn + j0), n1 = *(const float4*)(abn + j0 + 4);
      float W[8]  = {w0.x, w0.y, w0.z, w0.w, w1.x, w1.y, w1.z, w1.w};
      float G[8]  = {g0.x, g0.y, g0.z, g0.w, g1.x, g1.y, g1.z, g1.w};
      float Bn[8] = {n0.x, n0.y, n0.z, n0.w, n1.x, n1.y, n1.z, n1.w};
      #pragma unroll
      for (int j = 0; j < 8; ++j) {
        float hn = (cosv * W[j] + G[j]) * rr + Bn[j];
        v[j] = mk * silu_f(hn);
      }
    }
    short8 pk;
    #pragma unroll
    for (int j = 0; j < 8; ++j) pk[j] = (short)f2bf(v[j]);
    *(short8*)(sf + e * SFA + c0) = pk;
  }
  __syncthreads();

  // ---- GEMM1 (swapped): D[n][e] += W1eff x feat^T ; wave w owns nt = 3w..3w+2 ----
  const float maskv = smaskf[e31];
  f32x16 acc0, acc1, acc2;
  #pragma unroll
  for (int j = 0; j < 3; ++j) {
    const int nt = 3 * w + j;
    f32x16 a;
    #pragma unroll
    for (int rq = 0; rq < 4; ++rq) {
      const float4 bq = *(const float4*)(stab + nt * 32 + rq * 8 + hi * 4);
      const float4 cq = *(const float4*)(stab + 384 + nt * 32 + rq * 8 + hi * 4);
      a[rq * 4 + 0] = bq.x + maskv * cq.x;
      a[rq * 4 + 1] = bq.y + maskv * cq.y;
      a[rq * 4 + 2] = bq.z + maskv * cq.z;
      a[rq * 4 + 3] = bq.w + maskv * cq.w;
    }
    if (j == 0) acc0 = a; else if (j == 1) acc1 = a; else acc2 = a;
  }
  {
    const unsigned short* sfb = sf + e31 * SFA + hi * 8;
    const unsigned short* a0p = Bsw1 + ((((3 * w) * 24) * 64 + lane) << 3);
    #pragma unroll 4
    for (int kt = 0; kt < 24; ++kt) {
      short8 bfe = *(const short8*)(sfb + kt * 16);
      short8 a0 = *(const short8*)(a0p + kt * 512);
      short8 a1 = *(const short8*)(a0p + 12288 + kt * 512);
      short8 a2 = *(const short8*)(a0p + 24576 + kt * 512);
      acc0 = __builtin_amdgcn_mfma_f32_32x32x16_bf16(a0, bfe, acc0, 0, 0, 0);
      acc1 = __builtin_amdgcn_mfma_f32_32x32x16_bf16(a1, bfe, acc1, 0, 0, 0);
      acc2 = __builtin_amdgcn_mfma_f32_32x32x16_bf16(a2, bfe, acc2, 0, 0, 0);
    }
  }

  // ---- LN stats: per-lane sum over own 48 n-values + partner half + cross-wave ----
  {
    float s = 0.f, ss = 0.f;
    #pragma unroll
    for (int r = 0; r < 16; ++r) {
      s += acc0[r] + acc1[r] + acc2[r];
      ss += acc0[r] * acc0[r] + acc1[r] * acc1[r] + acc2[r] * acc2[r];
    }
    s += __shfl_xor(s, 32, 64);
    ss += __shfl_xor(ss, 32, 64);
    if (hi == 0) { ssum[w * 32 + e31] = s; ssq[w * 32 + e31] = ss; }
  }
  __syncthreads();
  if (t < 32) {
    float sm = ssum[t] + ssum[32 + t] + ssum[64 + t] + ssum[96 + t];
    float sq = ssq[t] + ssq[32 + t] + ssq[64 + t] + ssq[96 + t];
    float mean = sm * (1.f / 384.f);
    float var = sq * (1.f / 384.f) - mean * mean;
    smean[t] = mean; srstd[t] = rsqrtf(var + 1e-6f);
  }
  {  // zero zbuf (feat tile is dead; 32*ZST = 4128 floats)
    float4* zp = (float4*)zbuf;
    for (int i = t; i < 1032; i += 256) zp[i] = make_float4(0.f, 0.f, 0.f, 0.f);
  }
  __syncthreads();

  // ---- normalize+silu in-register, pack to GEMM2 B-frags via cvt_pk + permlane32_swap ----
  const float meanv = smean[e31], rstdv = srstd[e31];
  unsigned fr[6][4];
  #pragma unroll
  for (int j = 0; j < 3; ++j) {
    const int nt = 3 * w + j;
    f32x16 a = (j == 0) ? acc0 : (j == 1) ? acc1 : acc2;
    float f[16];
    #pragma unroll
    for (int rq = 0; rq < 4; ++rq) {
      const float4 gq = *(const float4*)(stab + 768 + nt * 32 + rq * 8 + hi * 4);
      const float4 bq = *(const float4*)(stab + 1152 + nt * 32 + rq * 8 + hi * 4);
      f[rq * 4 + 0] = silu_f((a[rq * 4 + 0] - meanv) * rstdv * gq.x + bq.x);
      f[rq * 4 + 1] = silu_f((a[rq * 4 + 1] - meanv) * rstdv * gq.y + bq.y);
      f[rq * 4 + 2] = silu_f((a[rq * 4 + 2] - meanv) * rstdv * gq.z + bq.z);
      f[rq * 4 + 3] = silu_f((a[rq * 4 + 3] - meanv) * rstdv * gq.w + bq.w);
    }
    unsigned P0 = cvtpk(f[0], f[1]),  P1 = cvtpk(f[2], f[3]);
    unsigned P2 = cvtpk(f[4], f[5]),  P3 = cvtpk(f[6], f[7]);
    unsigned P4 = cvtpk(f[8], f[9]),  P5 = cvtpk(f[10], f[11]);
    unsigned P6 = cvtpk(f[12], f[13]), P7 = cvtpk(f[14], f[15]);
    asm volatile("v_permlane32_swap_b32 %0, %1" : "+v"(P0), "+v"(P2));
    asm volatile("v_permlane32_swap_b32 %0, %1" : "+v"(P1), "+v"(P3));
    asm volatile("v_permlane32_swap_b32 %0, %1" : "+v"(P4), "+v"(P6));
    asm volatile("v_permlane32_swap_b32 %0, %1" : "+v"(P5), "+v"(P7));
    fr[2 * j][0] = P0; fr[2 * j][1] = P1; fr[2 * j][2] = P2; fr[2 * j][3] = P3;
    fr[2 * j + 1][0] = P4; fr[2 * j + 1][1] = P5; fr[2 * j + 1][2] = P6; fr[2 * j + 1][3] = P7;
  }

  // ---- GEMM2 split-K: wave w covers k = 96w..96w+95 (ktg = 6w..6w+5) ----
  f32x16 z0, z1, z2, z3;
  #pragma unroll
  for (int r = 0; r < 16; ++r) { z0[r] = 0.f; z1[r] = 0.f; z2[r] = 0.f; z3[r] = 0.f; }
  #pragma unroll
  for (int jk = 0; jk < 6; ++jk) {
    const int ktg = 6 * w + jk;
    union { unsigned u[4]; short8 s; } uu;
    uu.u[0] = fr[jk][0]; uu.u[1] = fr[jk][1]; uu.u[2] = fr[jk][2]; uu.u[3] = fr[jk][3];
    const short8 bop = uu.s;
    const unsigned short* bp = Bsw2 + ((ktg * 64 + lane) << 3);
    short8 wa0 = *(const short8*)(bp);
    short8 wa1 = *(const short8*)(bp + 12288);
    short8 wa2 = *(const short8*)(bp + 24576);
    short8 wa3 = *(const short8*)(bp + 36864);
    z0 = __builtin_amdgcn_mfma_f32_32x32x16_bf16(wa0, bop, z0, 0, 0, 0);
    z1 = __builtin_amdgcn_mfma_f32_32x32x16_bf16(wa1, bop, z1, 0, 0, 0);
    z2 = __builtin_amdgcn_mfma_f32_32x32x16_bf16(wa2, bop, z2, 0, 0, 0);
    z3 = __builtin_amdgcn_mfma_f32_32x32x16_bf16(wa3, bop, z3, 0, 0, 0);
  }
  #pragma unroll
  for (int r = 0; r < 16; ++r) {
    const int zz = (r & 3) + 8 * (r >> 2) + 4 * hi;
    atomicAdd(zbuf + e31 * ZST + zz, z0[r]);
    atomicAdd(zbuf + e31 * ZST + 32 + zz, z1[r]);
    atomicAdd(zbuf + e31 * ZST + 64 + zz, z2[r]);
    atomicAdd(zbuf + e31 * ZST + 96 + zz, z3[r]);
  }
  __syncthreads();

  // ---- scatter to node_out ----
  for (int i = t; i < 4096; i += 256) {
    const int e = i >> 7, zz = i & 127;
    const int ge = geb + e;
    if (ge < E)
      atomicAdd(node_out + (size_t)sdst[e] * 128 + zz, zbuf[e * ZST + zz] + stab[1536 + zz]);
  }
}

__global__ __launch_bounds__(256, 4)
void k_mrg(const float* __restrict__ node, const float* __restrict__ el,
           const int* __restrict__ src, const int* __restrict__ dst,
           const float* __restrict__ mb1, const float* __restrict__ mg,
           const float* __restrict__ mbn, const float* __restrict__ mb2,
           const unsigned short* __restrict__ Bsw3, const unsigned short* __restrict__ Bsw4,
           float* __restrict__ edge_out, int E) {
  __shared__ __attribute__((aligned(16))) unsigned short sf[32 * SFB];  // 20992 B; zbuf overlay
  __shared__ __attribute__((aligned(16))) float stab[512];  // mb1|mg|mbn|mb2
  __shared__ float ssum[128], ssq[128], smean[32], srstd[32];
  __shared__ int ssrc[32], sdst[32];

  const int t = threadIdx.x;
  const int lane = t & 63;
  const int w = t >> 6;
  const int e31 = lane & 31;
  const int hi = lane >> 5;
  const int geb = blockIdx.x * 32;
  float* zbuf = (float*)sf;

  for (int i = t; i < 512; i += 256) {
    float v;
    if (i < 128) v = mb1[i];
    else if (i < 256) v = mg[i - 128];
    else if (i < 384) v = mbn[i - 256];
    else v = mb2[i - 384];
    stab[i] = v;
  }
  if (t < 32) {
    int ge = geb + t;
    int ok = ge < E;
    ssrc[t] = ok ? src[ge] : 0;
    sdst[t] = ok ? dst[ge] : 0;
  }
  __syncthreads();

  // ---- stage [32][320]: node[src] | node[dst] | el ----
  #pragma unroll
  for (int ii = 0; ii < 5; ++ii) {
    int cid = t + 256 * ii;          // 1280 chunks
    int e = cid / 40, c0 = (cid % 40) * 8;
    int ge = geb + e;
    float v[8];
    const float* sp;
    if (c0 < 128)       sp = node + (size_t)ssrc[e] * 128 + c0;
    else if (c0 < 256)  sp = node + (size_t)sdst[e] * 128 + (c0 - 128);
    else                sp = el + (size_t)ge * 64 + (c0 - 256);
    if (ge < E) {
      float4 p0 = *(const float4*)sp;
      float4 p1 = *(const float4*)(sp + 4);
      v[0] = p0.x; v[1] = p0.y; v[2] = p0.z; v[3] = p0.w;
      v[4] = p1.x; v[5] = p1.y; v[6] = p1.z; v[7] = p1.w;
    } else {
      #pragma unroll
      for (int j = 0; j < 8; ++j) v[j] = 0.f;
    }
    short8 pk;
    #pragma unroll
    for (int j = 0; j < 8; ++j) pk[j] = (short)f2bf(v[j]);
    *(short8*)(sf + e * SFB + c0) = pk;
  }
  __syncthreads();

  // ---- GEMM1 (swapped): wave w owns nt = w (32 of 128 outputs), K = 320 ----
  f32x16 acc;
  #pragma unroll
  for (int rq = 0; rq < 4; ++rq) {
    const float4 bq = *(const float4*)(stab + w * 32 + rq * 8 + hi * 4);
    acc[rq * 4 + 0] = bq.x; acc[rq * 4 + 1] = bq.y;
    acc[rq * 4 + 2] = bq.z; acc[rq * 4 + 3] = bq.w;
  }
  {
    const unsigned short* sfb = sf + e31 * SFB + hi * 8;
    const unsigned short* ap = Bsw3 + (((w * 20) * 64 + lane) << 3);
    #pragma unroll 4
    for (int kt = 0; kt < 20; ++kt) {
      short8 bfe = *(const short8*)(sfb + kt * 16);
      short8 a0 = *(const short8*)(ap + kt * 512);
      acc = __builtin_amdgcn_mfma_f32_32x32x16_bf16(a0, bfe, acc, 0, 0, 0);
    }
  }

  {
    float s = 0.f, ss = 0.f;
    #pragma unroll
    for (int r = 0; r < 16; ++r) { s += acc[r]; ss += acc[r] * acc[r]; }
    s += __shfl_xor(s, 32, 64);
    ss += __shfl_xor(ss, 32, 64);
    if (hi == 0) { ssum[w * 32 + e31] = s; ssq[w * 32 + e31] = ss; }
  }
  __syncthreads();
  if (t < 32) {
    float sm = ssum[t] + ssum[32 + t] + ssum[64 + t] + ssum[96 + t];
    float sq = ssq[t] + ssq[32 + t] + ssq[64 + t] + ssq[96 + t];
    float mean = sm * (1.f / 128.f);
    float var = sq * (1.f / 128.f) - mean * mean;
    smean[t] = mean; srstd[t] = rsqrtf(var + 1e-6f);
  }
  {
    float4* zp = (float4*)zbuf;
    for (int i = t; i < 1032; i += 256) zp[i] = make_float4(0.f, 0.f, 0.f, 0.f);
  }
  __syncthreads();

  const float meanv = smean[e31], rstdv = srstd[e31];
  unsigned fr[2][4];
  {
    float f[16];
    #pragma unroll
    for (int rq = 0; rq < 4; ++rq) {
      const float4 gq = *(const float4*)(stab + 128 + w * 32 + rq * 8 + hi * 4);
      const float4 bq = *(const float4*)(stab + 256 + w * 32 + rq * 8 + hi * 4);
      f[rq * 4 + 0] = silu_f((acc[rq * 4 + 0] - meanv) * rstdv * gq.x + bq.x);
      f[rq * 4 + 1] = silu_f((acc[rq * 4 + 1] - meanv) * rstdv * gq.y + bq.y);
      f[rq * 4 + 2] = silu_f((acc[rq * 4 + 2] - meanv) * rstdv * gq.z + bq.z);
      f[rq * 4 + 3] = silu_f((acc[rq * 4 + 3] - meanv) * rstdv * gq.w + bq.w);
    }
    unsigned P0 = cvtpk(f[0], f[1]),  P1 = cvtpk(f[2], f[3]);
    unsigned P2 = cvtpk(f[4], f[5]),  P3 = cvtpk(f[6], f[7]);
    unsigned P4 = cvtpk(f[8], f[9]),  P5 = cvtpk(f[10], f[11]);
    unsigned P6 = cvtpk(f[12], f[13]), P7 = cvtpk(f[14], f[15]);
    asm volatile("v_permlane32_swap_b32 %0, %1" : "+v"(P0), "+v"(P2));
    asm volatile("v_permlane32_swap_b32 %0, %1" : "+v"(P1), "+v"(P3));
    asm volatile("v_permlane32_swap_b32 %0, %1" : "+v"(P4), "+v"(P6));
    asm volatile("v_permlane32_swap_b32 %0, %1" : "+v"(P5), "+v"(P7));
    fr[0][0] = P0; fr[0][1] = P1; fr[0][2] = P2; fr[0][3] = P3;
    fr[1][0] = P4; fr[1][1] = P5; fr[1][2] = P6; fr[1][3] = P7;
  }

  // ---- GEMM2 split-K: wave w covers k = 32w..32w+31 (ktg = 2w, 2w+1) ----
  f32x16 z0, z1, z2, z3;
  #pragma unroll
  for (int r = 0; r < 16; ++r) { z0[r] = 0.f; z1[r] = 0.f; z2[r] = 0.f; z3[r] = 0.f; }
  #pragma unroll
  for (int jk = 0; jk < 2; ++jk) {
    const int ktg = 2 * w + jk;
    union { unsigned u[4]; short8 s; } uu;
    uu.u[0] = fr[jk][0]; uu.u[1] = fr[jk][1]; uu.u[2] = fr[jk][2]; uu.u[3] = fr[jk][3];
    const short8 bop = uu.s;
    const unsigned short* bp = Bsw4 + ((ktg * 64 + lane) << 3);
    short8 wa0 = *(const short8*)(bp);
    short8 wa1 = *(const short8*)(bp + 4096);
    short8 wa2 = *(const short8*)(bp + 8192);
    short8 wa3 = *(const short8*)(bp + 12288);
    z0 = __builtin_amdgcn_mfma_f32_32x32x16_bf16(wa0, bop, z0, 0, 0, 0);
    z1 = __builtin_amdgcn_mfma_f32_32x32x16_bf16(wa1, bop, z1, 0, 0, 0);
    z2 = __builtin_amdgcn_mfma_f32_32x32x16_bf16(wa2, bop, z2, 0, 0, 0);
    z3 = __builtin_amdgcn_mfma_f32_32x32x16_bf16(wa3, bop, z3, 0, 0, 0);
  }
  #pragma unroll
  for (int r = 0; r < 16; ++r) {
    const int zz = (r & 3) + 8 * (r >> 2) + 4 * hi;
    atomicAdd(zbuf + e31 * ZST + zz, z0[r]);
    atomicAdd(zbuf + e31 * ZST + 32 + zz, z1[r]);
    atomicAdd(zbuf + e31 * ZST + 64 + zz, z2[r]);
    atomicAdd(zbuf + e31 * ZST + 96 + zz, z3[r]);
  }
  __syncthreads();

  for (int i = t; i < 4096; i += 256) {
    const int e = i >> 7, zz = i & 127;
    const int ge = geb + e;
    if (ge < E) edge_out[(size_t)ge * 128 + zz] = zbuf[e * ZST + zz] + stab[384 + zz];
  }
}

extern "C" void kernel_launch(void* const* d_in, const int* in_sizes, int n_in,
                              void* d_out, int out_size, void* d_ws, size_t ws_size,
                              hipStream_t stream) {
  const float* atom = (const float*)d_in[0];
  const float* el   = (const float*)d_in[1];
  const float* ev   = (const float*)d_in[2];
  const int*   eidx = (const int*)d_in[3];
  const float* aw1  = (const float*)d_in[4];
  const float* ab1  = (const float*)d_in[5];
  const float* ag   = (const float*)d_in[6];
  const float* abn  = (const float*)d_in[7];
  const float* aw2  = (const float*)d_in[8];
  const float* ab2  = (const float*)d_in[9];
  const float* iw1  = (const float*)d_in[10];
  const float* ib1  = (const float*)d_in[11];
  const float* ig   = (const float*)d_in[12];
  const float* ibn  = (const float*)d_in[13];
  const float* iw2  = (const float*)d_in[14];
  const float* ib2  = (const float*)d_in[15];
  const float* mw1  = (const float*)d_in[16];
  const float* mb1  = (const float*)d_in[17];
  const float* mg   = (const float*)d_in[18];
  const float* mbn  = (const float*)d_in[19];
  const float* mw2  = (const float*)d_in[20];
  const float* mb2  = (const float*)d_in[21];

  const int N = in_sizes[0] / 64;
  const int E = in_sizes[1] / 64;
  const int* src = eidx;
  const int* dst = eidx + E;

  char* ws = (char*)d_ws;
  size_t off = 0;
  int* last_idx = (int*)(ws + off);          off += 256;
  unsigned char* rawmask = (unsigned char*)(ws + off); off += ((size_t)E + 255) & ~(size_t)255;
  float* Wfa  = (float*)(ws + off);          off += (size_t)384 * 64 * 4;
  float* cfa  = (float*)(ws + off);          off += 384 * 4;
  float* wg   = (float*)(ws + off);          off += 256;
  float* bg   = (float*)(ws + off);          off += 256;
  float* angp = (float*)(ws + off);          off += 256;
  unsigned short* B1 = (unsigned short*)(ws + off); off += (size_t)12 * 24 * 64 * 8 * 2;
  unsigned short* B2 = (unsigned short*)(ws + off); off += (size_t)4 * 24 * 64 * 8 * 2;
  unsigned short* B3 = (unsigned short*)(ws + off); off += (size_t)4 * 20 * 64 * 8 * 2;
  unsigned short* B4 = (unsigned short*)(ws + off); off += (size_t)4 * 8 * 64 * 8 * 2;

  float* node_out = (float*)d_out;
  float* edge_out = node_out + (size_t)N * 128;

  const int eb = (E + 255) / 256;
  const int tb = (E + 31) / 32;
  const int swz_n = 12 * 24 * 64 + 4 * 24 * 64 + 4 * 20 * 64 + 4 * 8 * 64;

  k_init<<<2048, 256, 0, stream>>>(node_out, N * 128, last_idx);
  k_mask<<<eb, 256, 0, stream>>>(src, dst, E, rawmask, last_idx);
  k_setup<<<(384 * 64 + 384 + 64 + 255) / 256, 256, 0, stream>>>(
      iw1, aw2, ab2, aw1, ab1, ag, Wfa, cfa, wg, bg, angp);
  k_swz<<<(swz_n + 255) / 256, 256, 0, stream>>>(iw1, iw2, mw1, mw2, Wfa, B1, B2, B3, B4);
  k_inv<<<tb, 256, 0, stream>>>(atom, el, ev, src, dst, rawmask, last_idx,
                                ib1, ig, ibn, ib2, cfa, wg, bg, abn, angp,
                                B1, B2, node_out, E);
  k_mrg<<<tb, 256, 0, stream>>>(node_out, el, src, dst,
                                mb1, mg, mbn, mb2, B3, B4, edge_out, E);
}